// Round 7
// baseline (675.061 us; speedup 1.0000x reference)
//
#include <hip/hip_runtime.h>
#include <hip/hip_bf16.h>
#include <stdint.h>

// ---------------- problem constants ----------------
#define D_MODEL   1024
#define SEQ       8192
#define BATCH     4
#define NQKV      3072
#define HEADS     16

typedef _Float16 f16;
typedef f16   f16x8 __attribute__((ext_vector_type(8)));
typedef float f32x4 __attribute__((ext_vector_type(4)));

#define AS1 __attribute__((address_space(1)))
#define AS3 __attribute__((address_space(3)))

__device__ __forceinline__ void lds_load16(const void* g, void* l) {
  __builtin_amdgcn_global_load_lds((const AS1 void*)g, (AS3 void*)l, 16, 0, 0);
}

// ---------------------------------------------------------------------------
// Kernel 1: convert + reorder weights (fp32 -> fp16).
// ---------------------------------------------------------------------------
__global__ void cvt_weights(const float* __restrict__ wqkv,
                            const float* __restrict__ bqkv,
                            const float* __restrict__ wo,
                            f16* __restrict__ wqkvT,
                            float* __restrict__ bqkvR,
                            f16* __restrict__ woT)
{
  const int NW1 = NQKV * D_MODEL;      // 3145728
  const int NW2 = D_MODEL * D_MODEL;   // 1048576
  int i = blockIdx.x * 256 + threadIdx.x;
  if (i < NW1) {
    int c = i % NQKV, k = i / NQKV;            // coalesced read of wqkv
    int hh = c / 192, rr = c % 192;
    int t  = rr >> 6, a = rr & 63;
    int n  = t * 1024 + hh * 64 + a;
    wqkvT[(size_t)n * 1024 + k] = (f16)wqkv[i];
  } else if (i < NW1 + NW2) {
    int j = i - NW1;
    int n = j % D_MODEL, k = j / D_MODEL;      // coalesced read of wo
    woT[(size_t)n * 1024 + k] = (f16)wo[j];
  } else if (i < NW1 + NW2 + NQKV) {
    int c = i - NW1 - NW2;
    int hh = c / 192, rr = c % 192;
    int t  = rr >> 6, a = rr & 63;
    bqkvR[t * 1024 + hh * 64 + a] = bqkv[c];
  }
}

// ---------------------------------------------------------------------------
// Kernel 2: x fp32 -> fp16 with roll(-64).
// ---------------------------------------------------------------------------
__global__ void cvt_x(const float* __restrict__ x, f16* __restrict__ xb)
{
  int i  = blockIdx.x * 256 + threadIdx.x;  // one f16x8 per thread
  int r  = i >> 7;
  int c8 = i & 127;
  int bb = r >> 13, p = r & 8191;
  int sr = (bb << 13) | ((p + 64) & 8191);
  const float* src = x + (size_t)sr * 1024 + c8 * 8;
  float4 v0 = *(const float4*)(src);
  float4 v1 = *(const float4*)(src + 4);
  f16x8 o = { (f16)v0.x, (f16)v0.y, (f16)v0.z, (f16)v0.w,
              (f16)v1.x, (f16)v1.y, (f16)v1.z, (f16)v1.w };
  *(f16x8*)(xb + (size_t)r * 1024 + c8 * 8) = o;
}

// ---------------------------------------------------------------------------
// 256x256 8-phase NT GEMM, snake order + operand holding.
// C[M,N] = A[M,K]*B^T[N,K], K=1024. 512 thr = 8 waves (2m x 4n), per-wave
// 128x64. BK=64, 16 K-steps. LDS 128KB: 2 dbuf x {A0,A1,B0,B1} x 16KB.
// Phases (snake): (0,0) read A0+B0 [12 ds]; (0,1) read B1 [4];
// (1,1) read A1 [8]; (1,0) no reads (a1,b0 held in regs).
// 24 ds_read_b128/wave/step (minimum). Small per-phase read sets let the
// per-wave lgkm gates skew waves -> LDS drain overlaps MFMA (m201 mechanism).
// Stages: ph1 A1(t+1); ph2 A0(t+2); ph3 B0(t+2); ph4 B1(t+2); one counted
// vmcnt(6) per step at ph4 (drains tile t+1 exactly, keeps t+2 in flight).
// Ledger (audited r5+r6): WAR - every region staged >=1 barrier after its
// last ds_read's consuming MFMA; RAW - vmcnt invariant: entering step t,
// outstanding = {A0,B0,B1}(t+1) = 6 ops.
// ---------------------------------------------------------------------------
#define BARX() { asm volatile("" ::: "memory"); __builtin_amdgcn_s_barrier(); \
                 __builtin_amdgcn_sched_barrier(0); }

#define LOADAx(dst,d,qm) { _Pragma("unroll") for (int mi=0;mi<4;++mi){ \
    int rr = wm*64 + mi*16 + c16; \
    const char* p = lds + (d)*65536 + (qm)*16384 + rr*128; \
    _Pragma("unroll") for (int ks=0;ks<2;++ks) \
      dst[mi][ks] = *(const f16x8*)(p + ((((ks<<2)|g4) ^ (rr&7))<<4)); } }

#define LOADBx(dst,d,qn) { _Pragma("unroll") for (int nj=0;nj<2;++nj){ \
    int rr = wn*32 + nj*16 + c16; \
    const char* p = lds + (d)*65536 + 32768 + (qn)*16384 + rr*128; \
    _Pragma("unroll") for (int ks=0;ks<2;++ks) \
      dst[nj][ks] = *(const f16x8*)(p + ((((ks<<2)|g4) ^ (rr&7))<<4)); } }

#define MFC(AR,BR,qm,qn) { __builtin_amdgcn_s_setprio(1); \
    _Pragma("unroll") for (int mi=0;mi<4;++mi) \
    _Pragma("unroll") for (int nj=0;nj<2;++nj){ \
      acc[(qm)*4+mi][(qn)*2+nj] = __builtin_amdgcn_mfma_f32_16x16x32_f16( \
          AR[mi][0], BR[nj][0], acc[(qm)*4+mi][(qn)*2+nj], 0,0,0); \
      acc[(qm)*4+mi][(qn)*2+nj] = __builtin_amdgcn_mfma_f32_16x16x32_f16( \
          AR[mi][1], BR[nj][1], acc[(qm)*4+mi][(qn)*2+nj], 0,0,0); } \
    __builtin_amdgcn_s_setprio(0); }

template<int EPI>
__global__ __launch_bounds__(512, 2)
void gemm8(const f16* __restrict__ A, const f16* __restrict__ B,
           const float* __restrict__ bias,
           f16* __restrict__ outQ, f16* __restrict__ outK,
           f16* __restrict__ outVT, float* __restrict__ outF,
           int Ntiles)
{
  __shared__ alignas(16) char lds[131072];

  int nwg  = gridDim.x;                         // divisible by 8
  int work = ((int)blockIdx.x & 7) * (nwg >> 3) + ((int)blockIdx.x >> 3);
  int mt = work / Ntiles, nt = work % Ntiles;
  int m0 = mt * 256, n0 = nt * 256;

  int tid = threadIdx.x;
  int w = tid >> 6, lane = tid & 63;
  int wm = w >> 2, wn = w & 3;
  int c16 = lane & 15, g4 = lane >> 4;

  // staging: thread stages 16B chunk tid&7 of LDS row tid>>3 (and row+64 via
  // second issue); source chunk pre-XOR'd so LDS chunk j of row r holds
  // global chunk j^(r&7) (involution, rule #21).
  int rr0 = tid >> 3;
  int sc  = (((tid & 7) ^ ((tid >> 3) & 7)) << 4);
  const char* pA = (const char*)A + (size_t)(m0 + rr0) * 2048 + sc;
  const char* pB = (const char*)B + (size_t)(n0 + ((rr0 >> 5) << 6) + (rr0 & 31)) * 2048 + sc;
  char* dstA = lds + w * 1024;            // + d*65536 + qm*16384 (+8192)
  char* dstB = lds + 32768 + w * 1024;    // + d*65536 + qn*16384 (+8192)

  auto stageA = [&](int d, int qm, int t) {
    const char* s = pA + (size_t)(qm * 64) * 2048 + (size_t)t * 128;
    lds_load16(s,              dstA + d * 65536 + qm * 16384);
    lds_load16(s + 128 * 2048, dstA + d * 65536 + qm * 16384 + 8192);
  };
  auto stageB = [&](int d, int qn, int t) {
    const char* s = pB + (size_t)(qn * 32) * 2048 + (size_t)t * 128;
    lds_load16(s,              dstB + d * 65536 + qn * 16384);
    lds_load16(s + 128 * 2048, dstB + d * 65536 + qn * 16384 + 8192);
  };

  f32x4 acc[8][4];
#pragma unroll
  for (int i = 0; i < 8; ++i)
#pragma unroll
    for (int j = 0; j < 4; ++j)
      acc[i][j] = (f32x4){0.f, 0.f, 0.f, 0.f};
  f16x8 a0[4][2], a1[4][2], b0[2][2], b1[2][2];

  // prologue: tile0 all 4 halves (buf0) + tile1 A0,B0,B1 (buf1) = 14 ops;
  // vmcnt(6) drains exactly tile0, leaves tile1's 6 in flight.
  stageA(0, 0, 0); stageB(0, 0, 0); stageB(0, 1, 0); stageA(0, 1, 0);
  stageA(1, 0, 1); stageB(1, 0, 1); stageB(1, 1, 1);
  asm volatile("s_waitcnt vmcnt(6)" ::: "memory");
  BARX();

  for (int t = 0; t < 16; ++t) {
    int d = t & 1, e = d ^ 1;
    // ph1 (0,0): read A0,B0; stage A1(t+1)->buf e  [A1(e) last read (t-1,ph3)]
    LOADAx(a0, d, 0); LOADBx(b0, d, 0);
    if (t < 15) stageA(e, 1, t + 1);
    BARX(); MFC(a0, b0, 0, 0); BARX();
    // ph2 (0,1): read B1; stage A0(t+2)->buf d  [A0(d) last read (t,ph1)]
    LOADBx(b1, d, 1);
    if (t < 14) stageA(d, 0, t + 2);
    BARX(); MFC(a0, b1, 0, 1); BARX();
    // ph3 (1,1): read A1; stage B0(t+2)->buf d  [B0(d) last read (t,ph1)]
    LOADAx(a1, d, 1);
    if (t < 14) stageB(d, 0, t + 2);
    BARX(); MFC(a1, b1, 1, 1); BARX();
    // ph4 (1,0): no reads (a1,b0 held); stage B1(t+2)->buf d; counted vmcnt
    if (t < 14) {
      stageB(d, 1, t + 2);
      asm volatile("s_waitcnt vmcnt(6)" ::: "memory");  // tile t+1 landed
    } else if (t == 14) {
      asm volatile("s_waitcnt vmcnt(0)" ::: "memory");  // drain for last step
    }
    BARX(); MFC(a1, b0, 1, 0); BARX();
  }

  // ---------------- epilogue ----------------
  // row m = m0 + wm*128 + ai*16 + g4*4 + j ; col n = n0 + wn*64 + bj*16 + c16
  if (EPI == 0) {
    int tt = n0 >> 10;   // block-uniform: 0=Q, 1=K, 2=V
#pragma unroll
    for (int ai = 0; ai < 8; ++ai) {
#pragma unroll
      for (int bj = 0; bj < 4; ++bj) {
        int n  = n0 + wn * 64 + bj * 16 + c16;
        int nn = n & 1023;
        float bv = bias[n];
#pragma unroll
        for (int j = 0; j < 4; ++j) {
          int m = m0 + wm * 128 + ai * 16 + g4 * 4 + j;
          float v = acc[ai][bj][j] + bv;
          if (tt == 0) {
            outQ[(size_t)m * 1024 + nn] = (f16)v;
          } else if (tt == 1) {
            outK[(size_t)m * 1024 + nn] = (f16)v;
          } else {
            int sub = m >> 6, key = m & 63;
            int hh = nn >> 6, dk = nn & 63;
            outVT[(((size_t)(sub * 16 + hh) * 64 + dk) << 6) + key] = (f16)v;
          }
        }
      }
    }
  } else {
#pragma unroll
    for (int ai = 0; ai < 8; ++ai) {
#pragma unroll
      for (int bj = 0; bj < 4; ++bj) {
        int n = n0 + wn * 64 + bj * 16 + c16;
        float bv = bias[n];
#pragma unroll
        for (int j = 0; j < 4; ++j) {
          int m = m0 + wm * 128 + ai * 16 + g4 * 4 + j;
          int bb = m >> 13, p = m & 8191;
          int dr = (bb << 13) | ((p + 64) & 8191);   // roll(+64)
          outF[(size_t)dr * 1024 + n] = acc[ai][bj][j] + bv;
        }
      }
    }
  }
}

// ---------------------------------------------------------------------------
// Kernel 4: block-diagonal attention (unchanged, verified round 3/5).
// ---------------------------------------------------------------------------
__global__ __launch_bounds__(64)
void attn64(const f16* __restrict__ Q, const f16* __restrict__ Kb,
            const f16* __restrict__ VT, f16* __restrict__ O)
{
  __shared__ alignas(16) char plds[8192];   // P: [64][64] f16, swizzled
  int u = blockIdx.x;
  int sub = u >> 4, hh = u & 15;
  int l = threadIdx.x;
  int c = l & 15, g = l >> 4;

  const char* Qb = (const char*)Q  + (size_t)sub * 64 * 2048 + hh * 128;
  const char* KB = (const char*)Kb + (size_t)sub * 64 * 2048 + hh * 128;
  const char* VB = (const char*)VT + (size_t)u * 8192;

  f16x8 aq[4][2], bk[4][2];
#pragma unroll
  for (int mi = 0; mi < 4; ++mi)
#pragma unroll
    for (int kb = 0; kb < 2; ++kb)
      aq[mi][kb] = *(const f16x8*)(Qb + (mi * 16 + c) * 2048 + (kb * 32 + g * 8) * 2);
#pragma unroll
  for (int nj = 0; nj < 4; ++nj)
#pragma unroll
    for (int kb = 0; kb < 2; ++kb)
      bk[nj][kb] = *(const f16x8*)(KB + (nj * 16 + c) * 2048 + (kb * 32 + g * 8) * 2);

  f32x4 s[4][4];
#pragma unroll
  for (int mi = 0; mi < 4; ++mi)
#pragma unroll
    for (int nj = 0; nj < 4; ++nj)
      s[mi][nj] = (f32x4){0.f, 0.f, 0.f, 0.f};
#pragma unroll
  for (int kb = 0; kb < 2; ++kb)
#pragma unroll
    for (int mi = 0; mi < 4; ++mi)
#pragma unroll
      for (int nj = 0; nj < 4; ++nj)
        s[mi][nj] = __builtin_amdgcn_mfma_f32_16x16x32_f16(
            aq[mi][kb], bk[nj][kb], s[mi][nj], 0, 0, 0);

  const float SM_SCALE = 0.125f * 1.44269504089f;   // (1/sqrt(64))*log2(e)
#pragma unroll
  for (int mi = 0; mi < 4; ++mi) {
#pragma unroll
    for (int j = 0; j < 4; ++j) {
      float v0 = s[mi][0][j], v1 = s[mi][1][j], v2 = s[mi][2][j], v3 = s[mi][3][j];
      float mx = fmaxf(fmaxf(v0, v1), fmaxf(v2, v3));
      mx = fmaxf(mx, __shfl_xor(mx, 1));
      mx = fmaxf(mx, __shfl_xor(mx, 2));
      mx = fmaxf(mx, __shfl_xor(mx, 4));
      mx = fmaxf(mx, __shfl_xor(mx, 8));
      float p0 = exp2f((v0 - mx) * SM_SCALE);
      float p1 = exp2f((v1 - mx) * SM_SCALE);
      float p2 = exp2f((v2 - mx) * SM_SCALE);
      float p3 = exp2f((v3 - mx) * SM_SCALE);
      float sm = (p0 + p1) + (p2 + p3);
      sm += __shfl_xor(sm, 1);
      sm += __shfl_xor(sm, 2);
      sm += __shfl_xor(sm, 4);
      sm += __shfl_xor(sm, 8);
      float inv = 1.0f / sm;
      int r = mi * 16 + g * 4 + j;
      int rbyte = r * 128, rx = (r & 7) << 4;
      {
        int key = c;
        *(f16*)(plds + rbyte + (((key >> 3) << 4) ^ rx) + ((key & 7) << 1)) = (f16)(p0 * inv);
      }
      {
        int key = 16 + c;
        *(f16*)(plds + rbyte + (((key >> 3) << 4) ^ rx) + ((key & 7) << 1)) = (f16)(p1 * inv);
      }
      {
        int key = 32 + c;
        *(f16*)(plds + rbyte + (((key >> 3) << 4) ^ rx) + ((key & 7) << 1)) = (f16)(p2 * inv);
      }
      {
        int key = 48 + c;
        *(f16*)(plds + rbyte + (((key >> 3) << 4) ^ rx) + ((key & 7) << 1)) = (f16)(p3 * inv);
      }
    }
  }
  __syncthreads();

  f16x8 ap[4][2], bv[4][2];
#pragma unroll
  for (int mi = 0; mi < 4; ++mi) {
    int rowq = mi * 16 + c;
    int base = rowq * 128, rx = rowq & 7;
#pragma unroll
    for (int kb = 0; kb < 2; ++kb) {
      int ch = ((kb << 2) | g) ^ rx;
      ap[mi][kb] = *(const f16x8*)(plds + base + (ch << 4));
    }
  }
#pragma unroll
  for (int nj = 0; nj < 4; ++nj) {
    int dk = nj * 16 + c;
#pragma unroll
    for (int kb = 0; kb < 2; ++kb)
      bv[nj][kb] = *(const f16x8*)(VB + (dk * 64 + kb * 32 + g * 8) * 2);
  }

  f32x4 o[4][4];
#pragma unroll
  for (int mi = 0; mi < 4; ++mi)
#pragma unroll
    for (int nj = 0; nj < 4; ++nj)
      o[mi][nj] = (f32x4){0.f, 0.f, 0.f, 0.f};
#pragma unroll
  for (int kb = 0; kb < 2; ++kb)
#pragma unroll
    for (int mi = 0; mi < 4; ++mi)
#pragma unroll
      for (int nj = 0; nj < 4; ++nj)
        o[mi][nj] = __builtin_amdgcn_mfma_f32_16x16x32_f16(
            ap[mi][kb], bv[nj][kb], o[mi][nj], 0, 0, 0);

#pragma unroll
  for (int mi = 0; mi < 4; ++mi)
#pragma unroll
    for (int nj = 0; nj < 4; ++nj)
#pragma unroll
      for (int j = 0; j < 4; ++j) {
        int qrow = mi * 16 + g * 4 + j;
        int dk = nj * 16 + c;
        O[(size_t)(sub * 64 + qrow) * 1024 + hh * 64 + dk] = (f16)o[mi][nj][j];
      }
}

// ---------------------------------------------------------------------------
// launch
// ---------------------------------------------------------------------------
extern "C" void kernel_launch(void* const* d_in, const int* in_sizes, int n_in,
                              void* d_out, int out_size, void* d_ws, size_t ws_size,
                              hipStream_t stream)
{
  const float* x    = (const float*)d_in[0];
  const float* wqkv = (const float*)d_in[1];
  const float* bqkv = (const float*)d_in[2];
  const float* wo   = (const float*)d_in[3];
  const float* bo   = (const float*)d_in[4];
  float* out = (float*)d_out;
  char* ws = (char*)d_ws;

  // ws layout (bytes)
  f16*   xb    = (f16*)(ws + 0);            // 64MB (reused as A2 after GEMM1)
  f16*   wqkvT = (f16*)(ws + 67108864);     // 6MB
  float* bqkvR = (float*)(ws + 73400320);   // 12KB
  f16*   woT   = (f16*)(ws + 73412608);     // 2MB
  f16*   Qb    = (f16*)(ws + 75509760);     // 64MB
  f16*   Kb    = (f16*)(ws + 142618624);    // 64MB
  f16*   VTb   = (f16*)(ws + 209727488);    // 64MB -> total 276836352
  f16*   A2    = (f16*)(ws + 0);            // alias of xb (x dead after GEMM1)

  cvt_weights<<<16396, 256, 0, stream>>>(wqkv, bqkv, wo, wqkvT, bqkvR, woT);
  cvt_x<<<16384, 256, 0, stream>>>(x, xb);
  gemm8<0><<<1536, 512, 0, stream>>>(xb, wqkvT, bqkvR, Qb, Kb, VTb, nullptr, 12);
  attn64<<<8192, 64, 0, stream>>>(Qb, Kb, VTb, A2);
  gemm8<1><<<512, 512, 0, stream>>>(A2, woT, bo, nullptr, nullptr, nullptr, out, 4);
}

// Round 8
// 664.326 us; speedup vs baseline: 1.0162x; 1.0162x over previous
//
#include <hip/hip_runtime.h>
#include <hip/hip_bf16.h>
#include <stdint.h>

// ---------------- problem constants ----------------
#define D_MODEL   1024
#define SEQ       8192
#define BATCH     4
#define NQKV      3072
#define HEADS     16

typedef _Float16 f16;
typedef f16   f16x8 __attribute__((ext_vector_type(8)));
typedef float f32x4 __attribute__((ext_vector_type(4)));

#define AS1 __attribute__((address_space(1)))
#define AS3 __attribute__((address_space(3)))

__device__ __forceinline__ void lds_load16(const void* g, void* l) {
  __builtin_amdgcn_global_load_lds((const AS1 void*)g, (AS3 void*)l, 16, 0, 0);
}

// ---------------------------------------------------------------------------
// Kernel 1: convert + reorder weights (fp32 -> fp16).
// ---------------------------------------------------------------------------
__global__ void cvt_weights(const float* __restrict__ wqkv,
                            const float* __restrict__ bqkv,
                            const float* __restrict__ wo,
                            f16* __restrict__ wqkvT,
                            float* __restrict__ bqkvR,
                            f16* __restrict__ woT)
{
  const int NW1 = NQKV * D_MODEL;      // 3145728
  const int NW2 = D_MODEL * D_MODEL;   // 1048576
  int i = blockIdx.x * 256 + threadIdx.x;
  if (i < NW1) {
    int c = i % NQKV, k = i / NQKV;            // coalesced read of wqkv
    int hh = c / 192, rr = c % 192;
    int t  = rr >> 6, a = rr & 63;
    int n  = t * 1024 + hh * 64 + a;
    wqkvT[(size_t)n * 1024 + k] = (f16)wqkv[i];
  } else if (i < NW1 + NW2) {
    int j = i - NW1;
    int n = j % D_MODEL, k = j / D_MODEL;      // coalesced read of wo
    woT[(size_t)n * 1024 + k] = (f16)wo[j];
  } else if (i < NW1 + NW2 + NQKV) {
    int c = i - NW1 - NW2;
    int hh = c / 192, rr = c % 192;
    int t  = rr >> 6, a = rr & 63;
    bqkvR[t * 1024 + hh * 64 + a] = bqkv[c];
  }
}

// ---------------------------------------------------------------------------
// Kernel 2: x fp32 -> fp16 with roll(-64).
// ---------------------------------------------------------------------------
__global__ void cvt_x(const float* __restrict__ x, f16* __restrict__ xb)
{
  int i  = blockIdx.x * 256 + threadIdx.x;  // one f16x8 per thread
  int r  = i >> 7;
  int c8 = i & 127;
  int bb = r >> 13, p = r & 8191;
  int sr = (bb << 13) | ((p + 64) & 8191);
  const float* src = x + (size_t)sr * 1024 + c8 * 8;
  float4 v0 = *(const float4*)(src);
  float4 v1 = *(const float4*)(src + 4);
  f16x8 o = { (f16)v0.x, (f16)v0.y, (f16)v0.z, (f16)v0.w,
              (f16)v1.x, (f16)v1.y, (f16)v1.z, (f16)v1.w };
  *(f16x8*)(xb + (size_t)r * 1024 + c8 * 8) = o;
}

// ---------------------------------------------------------------------------
// 256x256 NT GEMM, 16 waves (4m x 4n), 4 waves/SIMD. C = A * B^T, K=1024.
// Per-wave output 64x64 (acc = 64 AGPR -> 16 waves fit at 128 reg cap).
// BK=64, 16 K-steps, LDS 128KB: 2 dbuf x {A0,A1 (16KB each), B0,B1}.
//   A-half q: rows with (row>>6)&1==q  (hr = (row&63) + ((row>>7)<<6))
//   B-half q: cols with (col>>5)&1==q  (hr = (col&31) + ((col>>6)<<5))
// 4 phases/step: (ks,nh) = (0,0),(0,1),(1,0),(1,1); reads 6/2/6/2 b128;
// 8 MFMA per phase; A frags held across nh pair. Phase interior is the m201
// template: reads; stages; s_barrier; lgkmcnt(0); setprio+MFMA; s_barrier.
// Stages: ph1 A1,B1(t+1)->buf e; ph4 A0,B0(t+2)->buf d + vmcnt(2) (tile t+1
// landed, t+2's 2 halves stay in flight). WAR: every stage >=1 barrier after
// its region's last reader (A0/A1 read ph1+ph3; B0 ph1/ph3; B1 ph2/ph4).
// ---------------------------------------------------------------------------
#define BARX() { asm volatile("" ::: "memory"); __builtin_amdgcn_s_barrier(); \
                 asm volatile("" ::: "memory"); }
#define LGKM0() asm volatile("s_waitcnt lgkmcnt(0)" ::: "memory");

#define LOADA(d,ks) { _Pragma("unroll") for (int mi=0;mi<4;++mi){ \
    int hr = hrA + mi*16; \
    const char* p = lds + (d)*65536 + qmA*16384 + hr*128; \
    af[mi] = *(const f16x8*)(p + ((((ks)<<2)|g4) ^ (hr&7))*16); } }

#define LOADB(d,ks,nh) { _Pragma("unroll") for (int nj2=0;nj2<2;++nj2){ \
    int hr = hrB + nj2*16; \
    const char* p = lds + (d)*65536 + 32768 + (nh)*16384 + hr*128; \
    bl[nj2] = *(const f16x8*)(p + ((((ks)<<2)|g4) ^ (hr&7))*16); } }

#define MF8(nh) { __builtin_amdgcn_s_setprio(1); \
    _Pragma("unroll") for (int mi=0;mi<4;++mi) \
    _Pragma("unroll") for (int nj2=0;nj2<2;++nj2) \
      acc[mi][(nh)*2+nj2] = __builtin_amdgcn_mfma_f32_16x16x32_f16( \
          af[mi], bl[nj2], acc[mi][(nh)*2+nj2], 0,0,0); \
    __builtin_amdgcn_s_setprio(0); }

template<int EPI>
__global__ __launch_bounds__(1024, 4)
void gemm16(const f16* __restrict__ A, const f16* __restrict__ B,
            const float* __restrict__ bias,
            f16* __restrict__ outQ, f16* __restrict__ outK,
            f16* __restrict__ outVT, float* __restrict__ outF,
            int Ntiles)
{
  __shared__ alignas(16) char lds[131072];

  int nwg  = gridDim.x;                         // divisible by 8
  int work = ((int)blockIdx.x & 7) * (nwg >> 3) + ((int)blockIdx.x >> 3);
  int mt = work / Ntiles, nt = work % Ntiles;
  int m0 = mt * 256, n0 = nt * 256;

  int tid = threadIdx.x;
  int w = tid >> 6, lane = tid & 63;
  int wm = w >> 2, wn = w & 3;
  int c16 = lane & 15, g4 = lane >> 4;
  int qmA = wm & 1;                    // which A-half this wave reads
  int hrA = (wm >> 1) * 64 + c16;      // + mi*16
  int hrB = wn * 32 + c16;             // + nj2*16

  // staging: 1024 threads stage one 16KB half per gload_lds instr.
  // thread tid -> LDS offset tid*16 (row rr0 = tid>>3, chunk tid&7);
  // source chunk pre-XOR'd: LDS chunk j of row r holds global chunk j^(r&7).
  int rr0 = tid >> 3;
  int sc  = (((tid & 7) ^ (rr0 & 7)) << 4);
  const char* pA = (const char*)A
      + (size_t)(m0 + (rr0 & 63) + ((rr0 >> 6) << 7)) * 2048 + sc;
  const char* pB = (const char*)B
      + (size_t)(n0 + (rr0 & 31) + ((rr0 >> 5) << 6)) * 2048 + sc;
  char* dstA = lds + w * 1024;            // + d*65536 + qm*16384
  char* dstB = lds + 32768 + w * 1024;    // + d*65536 + qn*16384

  auto stageA = [&](int d, int qm, int t) {
    lds_load16(pA + (size_t)qm * 131072 + (size_t)t * 128,
               dstA + d * 65536 + qm * 16384);
  };
  auto stageB = [&](int d, int qn, int t) {
    lds_load16(pB + (size_t)qn * 65536 + (size_t)t * 128,
               dstB + d * 65536 + qn * 16384);
  };

  f32x4 acc[4][4];
#pragma unroll
  for (int i = 0; i < 4; ++i)
#pragma unroll
    for (int j = 0; j < 4; ++j)
      acc[i][j] = (f32x4){0.f, 0.f, 0.f, 0.f};
  f16x8 af[4], bl[2];

  // prologue: tile0 all 4 halves (buf0) + tile1 A0,B0 (buf1);
  // vmcnt(2) drains exactly tile0, leaves tile1's 2 in flight.
  stageA(0, 0, 0); stageA(0, 1, 0); stageB(0, 0, 0); stageB(0, 1, 0);
  stageA(1, 0, 1); stageB(1, 0, 1);
  asm volatile("s_waitcnt vmcnt(2)" ::: "memory");
  BARX();

  for (int t = 0; t < 16; ++t) {
    int d = t & 1, e = d ^ 1;
    // ph1 (ks0,nh0): stage A1,B1(t+1)->buf e [last read (t-1) ph3/ph4]
    LOADA(d, 0); LOADB(d, 0, 0);
    if (t < 15) { stageA(e, 1, t + 1); stageB(e, 1, t + 1); }
    BARX(); LGKM0(); MF8(0); BARX();
    // ph2 (ks0,nh1): af held
    LOADB(d, 0, 1);
    BARX(); LGKM0(); MF8(1); BARX();
    // ph3 (ks1,nh0)
    LOADA(d, 1); LOADB(d, 1, 0);
    BARX(); LGKM0(); MF8(0); BARX();
    // ph4 (ks1,nh1): stage A0,B0(t+2)->buf d [last read this step's ph3];
    // counted vmcnt: {A0,B0}(t+1) + {A1,B1}(t+1) + 2 new = 6 -> keep 2.
    LOADB(d, 1, 1);
    if (t < 14) {
      stageA(d, 0, t + 2); stageB(d, 0, t + 2);
      asm volatile("s_waitcnt vmcnt(2)" ::: "memory");  // tile t+1 landed
    } else if (t == 14) {
      asm volatile("s_waitcnt vmcnt(0)" ::: "memory");  // drain for last step
    }
    BARX(); LGKM0(); MF8(1); BARX();
  }

  // ---------------- epilogue ----------------
  // row m = m0 + wm*64 + mi*16 + g4*4 + j ; col n = n0 + wn*64 + nj*16 + c16
  if (EPI == 0) {
    int tt = n0 >> 10;   // block-uniform: 0=Q, 1=K, 2=V
#pragma unroll
    for (int mi = 0; mi < 4; ++mi) {
#pragma unroll
      for (int nj = 0; nj < 4; ++nj) {
        int n  = n0 + wn * 64 + nj * 16 + c16;
        int nn = n & 1023;
        float bv = bias[n];
#pragma unroll
        for (int j = 0; j < 4; ++j) {
          int m = m0 + wm * 64 + mi * 16 + g4 * 4 + j;
          float v = acc[mi][nj][j] + bv;
          if (tt == 0) {
            outQ[(size_t)m * 1024 + nn] = (f16)v;
          } else if (tt == 1) {
            outK[(size_t)m * 1024 + nn] = (f16)v;
          } else {
            int sub = m >> 6, key = m & 63;
            int hh = nn >> 6, dk = nn & 63;
            outVT[(((size_t)(sub * 16 + hh) * 64 + dk) << 6) + key] = (f16)v;
          }
        }
      }
    }
  } else {
#pragma unroll
    for (int mi = 0; mi < 4; ++mi) {
#pragma unroll
      for (int nj = 0; nj < 4; ++nj) {
        int n = n0 + wn * 64 + nj * 16 + c16;
        float bv = bias[n];
#pragma unroll
        for (int j = 0; j < 4; ++j) {
          int m = m0 + wm * 64 + mi * 16 + g4 * 4 + j;
          int bb = m >> 13, p = m & 8191;
          int dr = (bb << 13) | ((p + 64) & 8191);   // roll(+64)
          outF[(size_t)dr * 1024 + n] = acc[mi][nj][j] + bv;
        }
      }
    }
  }
}

// ---------------------------------------------------------------------------
// Kernel 4: block-diagonal attention (unchanged, verified rounds 3/5/7).
// ---------------------------------------------------------------------------
__global__ __launch_bounds__(64)
void attn64(const f16* __restrict__ Q, const f16* __restrict__ Kb,
            const f16* __restrict__ VT, f16* __restrict__ O)
{
  __shared__ alignas(16) char plds[8192];   // P: [64][64] f16, swizzled
  int u = blockIdx.x;
  int sub = u >> 4, hh = u & 15;
  int l = threadIdx.x;
  int c = l & 15, g = l >> 4;

  const char* Qb = (const char*)Q  + (size_t)sub * 64 * 2048 + hh * 128;
  const char* KB = (const char*)Kb + (size_t)sub * 64 * 2048 + hh * 128;
  const char* VB = (const char*)VT + (size_t)u * 8192;

  f16x8 aq[4][2], bk[4][2];
#pragma unroll
  for (int mi = 0; mi < 4; ++mi)
#pragma unroll
    for (int kb = 0; kb < 2; ++kb)
      aq[mi][kb] = *(const f16x8*)(Qb + (mi * 16 + c) * 2048 + (kb * 32 + g * 8) * 2);
#pragma unroll
  for (int nj = 0; nj < 4; ++nj)
#pragma unroll
    for (int kb = 0; kb < 2; ++kb)
      bk[nj][kb] = *(const f16x8*)(KB + (nj * 16 + c) * 2048 + (kb * 32 + g * 8) * 2);

  f32x4 s[4][4];
#pragma unroll
  for (int mi = 0; mi < 4; ++mi)
#pragma unroll
    for (int nj = 0; nj < 4; ++nj)
      s[mi][nj] = (f32x4){0.f, 0.f, 0.f, 0.f};
#pragma unroll
  for (int kb = 0; kb < 2; ++kb)
#pragma unroll
    for (int mi = 0; mi < 4; ++mi)
#pragma unroll
      for (int nj = 0; nj < 4; ++nj)
        s[mi][nj] = __builtin_amdgcn_mfma_f32_16x16x32_f16(
            aq[mi][kb], bk[nj][kb], s[mi][nj], 0, 0, 0);

  const float SM_SCALE = 0.125f * 1.44269504089f;   // (1/sqrt(64))*log2(e)
#pragma unroll
  for (int mi = 0; mi < 4; ++mi) {
#pragma unroll
    for (int j = 0; j < 4; ++j) {
      float v0 = s[mi][0][j], v1 = s[mi][1][j], v2 = s[mi][2][j], v3 = s[mi][3][j];
      float mx = fmaxf(fmaxf(v0, v1), fmaxf(v2, v3));
      mx = fmaxf(mx, __shfl_xor(mx, 1));
      mx = fmaxf(mx, __shfl_xor(mx, 2));
      mx = fmaxf(mx, __shfl_xor(mx, 4));
      mx = fmaxf(mx, __shfl_xor(mx, 8));
      float p0 = exp2f((v0 - mx) * SM_SCALE);
      float p1 = exp2f((v1 - mx) * SM_SCALE);
      float p2 = exp2f((v2 - mx) * SM_SCALE);
      float p3 = exp2f((v3 - mx) * SM_SCALE);
      float sm = (p0 + p1) + (p2 + p3);
      sm += __shfl_xor(sm, 1);
      sm += __shfl_xor(sm, 2);
      sm += __shfl_xor(sm, 4);
      sm += __shfl_xor(sm, 8);
      float inv = 1.0f / sm;
      int r = mi * 16 + g * 4 + j;
      int rbyte = r * 128, rx = (r & 7) << 4;
      {
        int key = c;
        *(f16*)(plds + rbyte + (((key >> 3) << 4) ^ rx) + ((key & 7) << 1)) = (f16)(p0 * inv);
      }
      {
        int key = 16 + c;
        *(f16*)(plds + rbyte + (((key >> 3) << 4) ^ rx) + ((key & 7) << 1)) = (f16)(p1 * inv);
      }
      {
        int key = 32 + c;
        *(f16*)(plds + rbyte + (((key >> 3) << 4) ^ rx) + ((key & 7) << 1)) = (f16)(p2 * inv);
      }
      {
        int key = 48 + c;
        *(f16*)(plds + rbyte + (((key >> 3) << 4) ^ rx) + ((key & 7) << 1)) = (f16)(p3 * inv);
      }
    }
  }
  __syncthreads();

  f16x8 ap[4][2], bv[4][2];
#pragma unroll
  for (int mi = 0; mi < 4; ++mi) {
    int rowq = mi * 16 + c;
    int base = rowq * 128, rx = rowq & 7;
#pragma unroll
    for (int kb = 0; kb < 2; ++kb) {
      int ch = ((kb << 2) | g) ^ rx;
      ap[mi][kb] = *(const f16x8*)(plds + base + (ch << 4));
    }
  }
#pragma unroll
  for (int nj = 0; nj < 4; ++nj) {
    int dk = nj * 16 + c;
#pragma unroll
    for (int kb = 0; kb < 2; ++kb)
      bv[nj][kb] = *(const f16x8*)(VB + (dk * 64 + kb * 32 + g * 8) * 2);
  }

  f32x4 o[4][4];
#pragma unroll
  for (int mi = 0; mi < 4; ++mi)
#pragma unroll
    for (int nj = 0; nj < 4; ++nj)
      o[mi][nj] = (f32x4){0.f, 0.f, 0.f, 0.f};
#pragma unroll
  for (int kb = 0; kb < 2; ++kb)
#pragma unroll
    for (int mi = 0; mi < 4; ++mi)
#pragma unroll
      for (int nj = 0; nj < 4; ++nj)
        o[mi][nj] = __builtin_amdgcn_mfma_f32_16x16x32_f16(
            ap[mi][kb], bv[nj][kb], o[mi][nj], 0, 0, 0);

#pragma unroll
  for (int mi = 0; mi < 4; ++mi)
#pragma unroll
    for (int nj = 0; nj < 4; ++nj)
#pragma unroll
      for (int j = 0; j < 4; ++j) {
        int qrow = mi * 16 + g * 4 + j;
        int dk = nj * 16 + c;
        O[(size_t)(sub * 64 + qrow) * 1024 + hh * 64 + dk] = (f16)o[mi][nj][j];
      }
}

// ---------------------------------------------------------------------------
// launch
// ---------------------------------------------------------------------------
extern "C" void kernel_launch(void* const* d_in, const int* in_sizes, int n_in,
                              void* d_out, int out_size, void* d_ws, size_t ws_size,
                              hipStream_t stream)
{
  const float* x    = (const float*)d_in[0];
  const float* wqkv = (const float*)d_in[1];
  const float* bqkv = (const float*)d_in[2];
  const float* wo   = (const float*)d_in[3];
  const float* bo   = (const float*)d_in[4];
  float* out = (float*)d_out;
  char* ws = (char*)d_ws;

  // ws layout (bytes)
  f16*   xb    = (f16*)(ws + 0);            // 64MB (reused as A2 after GEMM1)
  f16*   wqkvT = (f16*)(ws + 67108864);     // 6MB
  float* bqkvR = (float*)(ws + 73400320);   // 12KB
  f16*   woT   = (f16*)(ws + 73412608);     // 2MB
  f16*   Qb    = (f16*)(ws + 75509760);     // 64MB
  f16*   Kb    = (f16*)(ws + 142618624);    // 64MB
  f16*   VTb   = (f16*)(ws + 209727488);    // 64MB -> total 276836352
  f16*   A2    = (f16*)(ws + 0);            // alias of xb (x dead after GEMM1)

  cvt_weights<<<16396, 256, 0, stream>>>(wqkv, bqkv, wo, wqkvT, bqkvR, woT);
  cvt_x<<<16384, 256, 0, stream>>>(x, xb);
  gemm16<0><<<1536, 1024, 0, stream>>>(xb, wqkvT, bqkvR, Qb, Kb, VTb, nullptr, 12);
  attn64<<<8192, 64, 0, stream>>>(Qb, Kb, VTb, A2);
  gemm16<1><<<512, 1024, 0, stream>>>(A2, woT, bo, nullptr, nullptr, nullptr, out, 4);
}